// Round 14
// baseline (10456.221 us; speedup 1.0000x reference)
//
#include <hip/hip_runtime.h>

typedef _Float16 half8 __attribute__((ext_vector_type(8)));
typedef float    f32x4 __attribute__((ext_vector_type(4)));

static constexpr int S_ = 2048;   // sequence length
static constexpr int B_ = 64;     // batch
static constexpr int D_ = 128;    // input dim
static constexpr int H_ = 256;    // hidden
static constexpr int C_ = 10;     // classes

static constexpr int NBLK = 64;   // 32 L1-role + 32 L2-role (R8 structure)
static constexpr int NTHR = 512;  // 8 waves (R8/R11-exact wave structure)
static constexpr int HHALF = B_ * H_;   // halves per h slot (32 KB)

// R22 = R19 (best, 8815 us; R21's role-rebalance reverted) + WARM-LLC
// PREFETCH of next-iteration operand planes:
//   Hypothesis (fits R14/R19/R20 evidence + the stubborn 0.6 MB/iter FETCH
//   excess): sc0 sc1 stores are write-through NO-ALLOCATE -> publish data
//   lands in HBM; the producer drain waits an HBM-class ack and each fresh
//   line's FIRST consumer fetches from HBM (~2000cy).
//   Fix attempt: idle tail waves issue PLAIN cached loads (dead results)
//   over the planes the block reads next iteration. A plain load allocates
//   the line at the coherence point; the producer's write-through UPDATES
//   the resident line; the consumer's sc1 load then hits LLC. Staleness at
//   prefetch time is harmless (dead results; consumer coherence is carried
//   by sc1 semantics). Prefetch drain lands on the join barrier's implicit
//   vmcnt(0), CONCURRENT with wave 0's publish drain.
//   Coverage: L1 waves 2-5 -> h1raw[next r1] (512 lines, 2/lane);
//             L2 wave 7    -> h1t[next r1]   (512 lines, 8/lane);
//             L2 wave 1    -> h2raw[next r2] (post-poll; 8/lane).
//
// Per-block epoch flags, one 64B line each (R7/R8-proven).
__device__ __attribute__((aligned(64))) unsigned g_f[NBLK * 16];

#define LD_AG(p)    __hip_atomic_load((p), __ATOMIC_RELAXED, __HIP_MEMORY_SCOPE_AGENT)
#define ST_AG(p, v) __hip_atomic_store((p), (v), __ATOMIC_RELAXED, __HIP_MEMORY_SCOPE_AGENT)

__device__ __forceinline__ float fs(float v) { return 1.0f / (1.0f + __expf(-v)); }
__device__ __forceinline__ float ft(float v) { return 1.0f - 2.0f / (__expf(2.0f * v) + 1.0f); }

// 8x 16B LLC-coherent loads in ONE asm block, completed by the trailing
// vmcnt(0): the compiler/RA can never read an un-landed destination register.
__device__ __forceinline__ void ldg16x8(half8* r,
    const _Float16* p0, const _Float16* p1, const _Float16* p2, const _Float16* p3,
    const _Float16* p4, const _Float16* p5, const _Float16* p6, const _Float16* p7)
{
    asm volatile(
        "global_load_dwordx4 %0, %8, off sc0 sc1\n\t"
        "global_load_dwordx4 %1, %9, off sc0 sc1\n\t"
        "global_load_dwordx4 %2, %10, off sc0 sc1\n\t"
        "global_load_dwordx4 %3, %11, off sc0 sc1\n\t"
        "global_load_dwordx4 %4, %12, off sc0 sc1\n\t"
        "global_load_dwordx4 %5, %13, off sc0 sc1\n\t"
        "global_load_dwordx4 %6, %14, off sc0 sc1\n\t"
        "global_load_dwordx4 %7, %15, off sc0 sc1\n\t"
        "s_waitcnt vmcnt(0)"
        : "=&v"(r[0]), "=&v"(r[1]), "=&v"(r[2]), "=&v"(r[3]),
          "=&v"(r[4]), "=&v"(r[5]), "=&v"(r[6]), "=&v"(r[7])
        : "v"(p0), "v"(p1), "v"(p2), "v"(p3),
          "v"(p4), "v"(p5), "v"(p6), "v"(p7)
        : "memory");
}

// 16x 16B LLC-coherent loads (8 fragments from pa, 8 from pb; fragment stride
// 4096 B) in ONE asm block with ONE trailing vmcnt(0) (R14-proven).
__device__ __forceinline__ void ldg16x8x2(half8* r,
                                          const _Float16* pa, const _Float16* pb)
{
    const _Float16* a0 = pa + 2048;  const _Float16* a1 = pa + 6144;
    const _Float16* a2 = pa + 10240; const _Float16* a3 = pa + 14336;
    const _Float16* b0 = pb + 2048;  const _Float16* b1 = pb + 6144;
    const _Float16* b2 = pb + 10240; const _Float16* b3 = pb + 14336;
    asm volatile(
        "global_load_dwordx4 %0, %16, off offset:-4096 sc0 sc1\n\t"
        "global_load_dwordx4 %1, %16, off sc0 sc1\n\t"
        "global_load_dwordx4 %2, %17, off offset:-4096 sc0 sc1\n\t"
        "global_load_dwordx4 %3, %17, off sc0 sc1\n\t"
        "global_load_dwordx4 %4, %18, off offset:-4096 sc0 sc1\n\t"
        "global_load_dwordx4 %5, %18, off sc0 sc1\n\t"
        "global_load_dwordx4 %6, %19, off offset:-4096 sc0 sc1\n\t"
        "global_load_dwordx4 %7, %19, off sc0 sc1\n\t"
        "global_load_dwordx4 %8, %20, off offset:-4096 sc0 sc1\n\t"
        "global_load_dwordx4 %9, %20, off sc0 sc1\n\t"
        "global_load_dwordx4 %10, %21, off offset:-4096 sc0 sc1\n\t"
        "global_load_dwordx4 %11, %21, off sc0 sc1\n\t"
        "global_load_dwordx4 %12, %22, off offset:-4096 sc0 sc1\n\t"
        "global_load_dwordx4 %13, %22, off sc0 sc1\n\t"
        "global_load_dwordx4 %14, %23, off offset:-4096 sc0 sc1\n\t"
        "global_load_dwordx4 %15, %23, off sc0 sc1\n\t"
        "s_waitcnt vmcnt(0)"
        : "=&v"(r[0]),  "=&v"(r[1]),  "=&v"(r[2]),  "=&v"(r[3]),
          "=&v"(r[4]),  "=&v"(r[5]),  "=&v"(r[6]),  "=&v"(r[7]),
          "=&v"(r[8]),  "=&v"(r[9]),  "=&v"(r[10]), "=&v"(r[11]),
          "=&v"(r[12]), "=&v"(r[13]), "=&v"(r[14]), "=&v"(r[15])
        : "v"(a0), "v"(a1), "v"(a2), "v"(a3),
          "v"(b0), "v"(b1), "v"(b2), "v"(b3)
        : "memory");
}

// 2x 16B LLC-coherent loads, one vmcnt (head path; R17/R18-verified).
__device__ __forceinline__ void ldg16x2(half8* r,
                                        const _Float16* p0, const _Float16* p1)
{
    asm volatile(
        "global_load_dwordx4 %0, %2, off sc0 sc1\n\t"
        "global_load_dwordx4 %1, %3, off sc0 sc1\n\t"
        "s_waitcnt vmcnt(0)"
        : "=&v"(r[0]), "=&v"(r[1])
        : "v"(p0), "v"(p1)
        : "memory");
}

// 16B LLC-coherent store (publish path; R12/R14/R16-verified). The caller's
// trailing s_waitcnt vmcnt(0) orders it before the flag store.
__device__ __forceinline__ void stg16(_Float16* p, half8 v) {
    asm volatile("global_store_dwordx4 %0, %1, off sc0 sc1"
                 :: "v"(p), "v"(v) : "memory");
}

// Warm-LLC prefetch helpers: PLAIN cached loads, dead results, no waitcnt
// (the join barrier's implicit vmcnt(0) drains them, concurrent with the
// publish drain). Allocation-only; coherence is unaffected.
__device__ __forceinline__ void pf2(const char* p) {
    unsigned d0, d1;
    asm volatile(
        "global_load_dword %0, %2, off\n\t"
        "global_load_dword %1, %2, off offset:64"
        : "=&v"(d0), "=&v"(d1) : "v"(p) : "memory");
}
__device__ __forceinline__ void pf8(const char* p) {
    unsigned d[8];
    asm volatile(
        "global_load_dword %0, %8, off\n\t"
        "global_load_dword %1, %8, off offset:64\n\t"
        "global_load_dword %2, %8, off offset:128\n\t"
        "global_load_dword %3, %8, off offset:192\n\t"
        "global_load_dword %4, %8, off offset:256\n\t"
        "global_load_dword %5, %8, off offset:320\n\t"
        "global_load_dword %6, %8, off offset:384\n\t"
        "global_load_dword %7, %8, off offset:448"
        : "=&v"(d[0]), "=&v"(d[1]), "=&v"(d[2]), "=&v"(d[3]),
          "=&v"(d[4]), "=&v"(d[5]), "=&v"(d[6]), "=&v"(d[7])
        : "v"(p) : "memory");
}

__device__ __forceinline__ half8 cvt8(float4 a, float4 b) {
    half8 r;
    r[0] = (_Float16)a.x; r[1] = (_Float16)a.y; r[2] = (_Float16)a.z; r[3] = (_Float16)a.w;
    r[4] = (_Float16)b.x; r[5] = (_Float16)b.y; r[6] = (_Float16)b.z; r[7] = (_Float16)b.w;
    return r;
}

__global__ __launch_bounds__(NTHR, 1)
void lstm2_ef(const float* __restrict__ x,
              const float* __restrict__ Wih1, const float* __restrict__ Whh1,
              const float* __restrict__ b1,
              const float* __restrict__ Wih2, const float* __restrict__ Whh2,
              const float* __restrict__ b2,
              const float* __restrict__ Wlin, const float* __restrict__ blin,
              float* __restrict__ out, _Float16* __restrict__ hb)
{
    const int bid = blockIdx.x, tid = threadIdx.x;
    const bool isL2 = (bid >= 32);
    const int blk  = bid & 31;                   // 0..31 within role
    const int lane = tid & 63, w = tid >> 6;     // 8 waves
    const int mt   = w & 3;                      // M-tile: batches mt*16..+15
    const int nt   = w >> 2;                     // N-tile 0/1
    const int n    = lane & 15;                  // n-row within tile
    const int kg   = lane >> 4;                  // k-group 0..3
    const int c4   = n >> 2, gate = n & 3;       // n = col4*4 + gate
    const int lc   = nt * 4 + c4;                // local col 0..7
    const int col  = blk * 8 + lc;               // hidden column 0..255
    const int rowg = gate * H_ + col;            // global W gate-row
    const int batchA = mt * 16 + n;              // A-frag row = batch

    _Float16* h1raw = hb;                 // [3][HHALF] each
    _Float16* h1t   = hb + 3 * HHALF;
    _Float16* h2raw = hb + 6 * HHALF;
    _Float16* h2t   = hb + 9 * HHALF;

    __shared__ __align__(16) _Float16 sh[2][B_][8];   // [raw|tanh][batch][local col]

    const unsigned base = LD_AG(&g_f[bid * 16]);   // uniform at launch boundary

    // zero h state via agent-scope stores: 12 slots * 32 KB = 49152 doubles
    { double* z = (double*)hb;
      for (int i = bid * NTHR + tid; i < 49152; i += NBLK * NTHR) ST_AG(z + i, 0.0); }

    // ---- weight-stationary B-fragments in VGPRs (loaded once; R8-verbatim) ----
    half8 bfrag[16];
    if (!isL2) {
        #pragma unroll
        for (int kt = 0; kt < 4; ++kt) {     // Wih1 [4H][128]
            const float* p = Wih1 + (size_t)rowg * D_ + kt * 32 + kg * 8;
            bfrag[kt] = cvt8(*(const float4*)p, *(const float4*)(p + 4));
        }
        #pragma unroll
        for (int kt = 4; kt < 12; ++kt) {    // Whh1 [4H][256]
            const float* p = Whh1 + (size_t)rowg * H_ + (kt - 4) * 32 + kg * 8;
            bfrag[kt] = cvt8(*(const float4*)p, *(const float4*)(p + 4));
        }
    } else {
        #pragma unroll
        for (int kt = 0; kt < 8; ++kt) {     // Wih2 [4H][256]
            const float* p = Wih2 + (size_t)rowg * H_ + kt * 32 + kg * 8;
            bfrag[kt] = cvt8(*(const float4*)p, *(const float4*)(p + 4));
        }
        #pragma unroll
        for (int kt = 8; kt < 16; ++kt) {    // Whh2 [4H][256]
            const float* p = Whh2 + (size_t)rowg * H_ + (kt - 8) * 32 + kg * 8;
            bfrag[kt] = cvt8(*(const float4*)p, *(const float4*)(p + 4));
        }
    }
    const float bias_n = isL2 ? b2[rowg] : b1[rowg];

    // publish init (zero-state visible): all waves' zero stores must be acked
    __syncthreads();                 // full-block vmcnt(0) drain before barrier
    if (tid == 0) ST_AG(&g_f[bid * 16], base + 1u);

    float cr[4] = {0.f, 0.f, 0.f, 0.f};   // cell state

    // x prefetch registers (L1 blocks only): FULL x fragments for t (R16)
    float4 xf[8];
    if (!isL2) {
        const float* xr = x + (size_t)batchA * D_;   // t = 0
        #pragma unroll
        for (int q = 0; q < 4; ++q) {
            xf[2 * q]     = *(const float4*)(xr + q * 32 + kg * 8);
            xf[2 * q + 1] = *(const float4*)(xr + q * 32 + kg * 8 + 4);
        }
    }

    // ---- prologue poll for iteration 0 (original t==0 semantics: all
    // targets et1 = base+1, since zero-init was written by ALL blocks) ----
    {
        const unsigned et1 = base + 1u;
        if (tid >= 64 && tid < 128) {
            while ((int)(LD_AG(&g_f[(tid & 63) * 16]) - et1) < 0)
                __builtin_amdgcn_s_sleep(1);
        }
        __syncthreads();
    }

    int w3 = 0;   // t % 3

    // iteration t: L1 computes h1[t] (slot w3); L2 computes h2[t-1] (slot r1)
    // reading h1t[r1], h2raw[r2]; head (on L2) computes out[t-2] from h2t[r2].
    // Entry invariant: the poll for iteration t passed before the barrier
    // that precedes this iteration's compute.
    for (int t = 0; t <= S_ + 1; ++t) {
        const int r1 = (w3 == 0) ? 2 : w3 - 1;   // (t-1) % 3
        const int r2 = (w3 == 2) ? 0 : w3 + 1;   // (t-2) % 3

        if (!isL2) {
            if (t < S_) {
                half8 af[12];
                {   // x part: ALL from prefetch registers (no loads on chain)
                    af[0] = cvt8(xf[0], xf[1]);
                    af[1] = cvt8(xf[2], xf[3]);
                    af[2] = cvt8(xf[4], xf[5]);
                    af[3] = cvt8(xf[6], xf[7]);
                }
                // h part: K-tile (kt,kg) -> block region jb = kt*4+kg;
                // kt stride in halves = 4*64*8 = 2048
                const _Float16* hp = h1raw + r1 * HHALF + (((size_t)kg * 64 + batchA) << 3);
                ldg16x8(&af[4], hp,          hp + 2048,  hp + 4096,  hp + 6144,
                                hp + 8192,   hp + 10240, hp + 12288, hp + 14336);
                f32x4 accA = {0.f, 0.f, 0.f, 0.f}, accB = {0.f, 0.f, 0.f, 0.f};
                #pragma unroll
                for (int kt = 0; kt < 12; kt += 2) {
                    accA = __builtin_amdgcn_mfma_f32_16x16x32_f16(af[kt],     bfrag[kt],     accA, 0, 0, 0);
                    accB = __builtin_amdgcn_mfma_f32_16x16x32_f16(af[kt + 1], bfrag[kt + 1], accB, 0, 0, 0);
                }
                #pragma unroll
                for (int r = 0; r < 4; ++r) {
                    const float pre = accA[r] + accB[r] + bias_n;
                    const float av  = (gate == 2) ? ft(pre) : fs(pre);
                    const int lb = (lane & 48) | (c4 << 2);
                    const float gi = __shfl(av, lb | 0, 64), gf = __shfl(av, lb | 1, 64);
                    const float gg = __shfl(av, lb | 2, 64), go = __shfl(av, lb | 3, 64);
                    const float cn = gf * cr[r] + gi * gg; cr[r] = cn;
                    const float hv = go * ft(cn);
                    const int bD = mt * 16 + kg * 4 + r;
                    if (gate == 0) sh[0][bD][lc] = (_Float16)hv;
                    if (gate == 1) sh[1][bD][lc] = (_Float16)ft(hv);
                }
            }
        } else {
            if (t >= 1 && t <= S_) {
                half8 af[16];
                const _Float16* h1p = h1t   + r1 * HHALF + (((size_t)kg * 64 + batchA) << 3);
                const _Float16* h2p = h2raw + r2 * HHALF + (((size_t)kg * 64 + batchA) << 3);
                ldg16x8x2(af, h1p, h2p);   // all 16 fragments, ONE vmcnt(0)
                f32x4 accA = {0.f, 0.f, 0.f, 0.f}, accB = {0.f, 0.f, 0.f, 0.f};
                #pragma unroll
                for (int kt = 0; kt < 16; kt += 2) {
                    accA = __builtin_amdgcn_mfma_f32_16x16x32_f16(af[kt],     bfrag[kt],     accA, 0, 0, 0);
                    accB = __builtin_amdgcn_mfma_f32_16x16x32_f16(af[kt + 1], bfrag[kt + 1], accB, 0, 0, 0);
                }
                #pragma unroll
                for (int r = 0; r < 4; ++r) {
                    const float pre = accA[r] + accB[r] + bias_n;
                    const float av  = (gate == 2) ? ft(pre) : fs(pre);
                    const int lb = (lane & 48) | (c4 << 2);
                    const float gi = __shfl(av, lb | 0, 64), gf = __shfl(av, lb | 1, 64);
                    const float gg = __shfl(av, lb | 2, 64), go = __shfl(av, lb | 3, 64);
                    const float cn = gf * cr[r] + gi * gg; cr[r] = cn;
                    const float hv = go * ft(cn);
                    const int bD = mt * 16 + kg * 4 + r;
                    if (gate == 0) sh[0][bD][lc] = (_Float16)hv;
                    if (gate == 1) sh[1][bD][lc] = (_Float16)ft(hv);
                }
            }
        }

        __syncthreads();   // LDS tile complete (lgkm drain + barrier)

        // ---- wave 0: publish + drain + EARLY FLAG ----
        if (tid < 64) {
            const int b = tid;
            bool doit; int slot;
            if (!isL2) { doit = (t < S_);            slot = w3; }
            else       { doit = (t >= 1 && t <= S_); slot = r1; }
            if (doit) {
                const half8 s0 = *(const half8*)&sh[0][b][0];
                const half8 s1 = *(const half8*)&sh[1][b][0];
                _Float16* braw = isL2 ? h2raw : h1raw;
                _Float16* btnh = isL2 ? h2t   : h1t;
                stg16(braw + slot * HHALF + ((blk * 64 + b) << 3), s0);
                stg16(btnh + slot * HHALF + ((blk * 64 + b) << 3), s1);
            }
            asm volatile("s_waitcnt vmcnt(0)" ::: "memory");
            __builtin_amdgcn_sched_barrier(0);
            if (tid == 0) ST_AG(&g_f[bid * 16], base + (unsigned)t + 2u);
        }

        // ---- wave 1: poll for iteration t+1, CONCURRENT with wave 0's
        // publish+drain (different lines). Targets = original scheme at t+1
        // (t+1 >= 1, so no t==0 case). Skipped after the last iteration. ----
        if (t < S_ + 1 && tid >= 64 && tid < 128) {
            const int l = tid & 63;
            const unsigned et1 = base + (unsigned)(t + 1) + 1u;
            const unsigned tg = (l < 32 || isL2) ? et1 : et1 - 1u;
            while ((int)(LD_AG(&g_f[l * 16]) - tg) < 0)
                __builtin_amdgcn_s_sleep(1);   // backoff: cut hot-line polls
        }
        // L2 wave 1 (post-poll): warm-LLC prefetch of next iteration's
        // h2raw plane (next r2 = current r1). 512 lines, 8/lane.
        if (isL2 && t + 1 <= S_ && w == 1)
            pf8((const char*)(h2raw + r1 * HHALF) + (lane << 9));

        // ---- post-flag work: overlaps peers' detect+load window ----
        // x prefetch for t+1 (L1 role): FULL fragments (all waves; wave 1
        // does it after its poll)
        if (!isL2 && t + 1 < S_) {
            const float* xr = x + ((size_t)(t + 1) * B_ + batchA) * D_;
            #pragma unroll
            for (int q = 0; q < 4; ++q) {
                xf[2 * q]     = *(const float4*)(xr + q * 32 + kg * 8);
                xf[2 * q + 1] = *(const float4*)(xr + q * 32 + kg * 8 + 4);
            }
        }
        // L1 waves 2-5: warm-LLC prefetch of next iteration's h1raw plane
        // (next r1 = current w3). 512 lines, 2/lane across 256 lanes.
        if (!isL2 && t + 1 < S_ && w >= 2 && w <= 5)
            pf2((const char*)(h1raw + w3 * HHALF) + (((((w - 2) << 6) | lane)) << 7));
        // L2 wave 7: warm-LLC prefetch of next iteration's h1t plane
        // (next r1 = current w3). 512 lines, 8/lane.
        if (isL2 && t + 1 <= S_ && w == 7)
            pf8((const char*)(h1t + w3 * HHALF) + (lane << 9));

        // head (on L2, waves 2-6): out[t-2] = sigmoid(tanh(h2[t-2])@Wlin^T+blin)
        // Off waves 0/1 (publish and poll). Race-free: head(t) precedes our
        // flag(t+1), which gates any peer overwrite of h2t slot r2.
        if (isL2 && t >= 2) {
            const int hg = (tid >> 4) - 8;   // waves 2-6: groups 0..19
            if (hg >= 0 && hg < 20) {
                const int dot = blk * 20 + hg, cls = dot >> 6, ob = dot & 63, l16 = tid & 15;
                const _Float16* hB = h2t + r2 * HHALF;
                half8 v[2];
                ldg16x2(v, hB + (((2 * l16)     * 64 + ob) << 3),
                           hB + (((2 * l16 + 1) * 64 + ob) << 3));
                const float* wr = Wlin + (size_t)cls * H_ + l16 * 16;
                float p = 0.f;
                #pragma unroll
                for (int j = 0; j < 8; ++j) p += (float)v[0][j] * wr[j] + (float)v[1][j] * wr[8 + j];
                p += __shfl_xor(p, 1, 64); p += __shfl_xor(p, 2, 64);
                p += __shfl_xor(p, 4, 64); p += __shfl_xor(p, 8, 64);
                if (l16 == 0)
                    out[((size_t)(t - 2) * B_ + ob) * C_ + cls] = fs(p + blin[cls]);
            }
        }

        // join: wave 1's poll passed AND wave 0's publish drained+flagged.
        // The implicit vmcnt(0) here also drains the warm-LLC prefetches,
        // concurrent with the publish drain. Orders LDS-tile reuse and slot
        // overwrites for iteration t+1.
        __syncthreads();

        w3 = r2;   // (t+1) % 3
    }
}

extern "C" void kernel_launch(void* const* d_in, const int* in_sizes, int n_in,
                              void* d_out, int out_size, void* d_ws, size_t ws_size,
                              hipStream_t stream)
{
    const float* x    = (const float*)d_in[0];
    const float* Wih1 = (const float*)d_in[1];
    const float* Whh1 = (const float*)d_in[2];
    const float* b1   = (const float*)d_in[3];
    const float* Wih2 = (const float*)d_in[4];
    const float* Whh2 = (const float*)d_in[5];
    const float* b2   = (const float*)d_in[6];
    const float* Wlin = (const float*)d_in[7];
    const float* blin = (const float*)d_in[8];
    float* out = (float*)d_out;
    _Float16* hb = (_Float16*)d_ws;

    void* args[] = { (void*)&x, (void*)&Wih1, (void*)&Whh1, (void*)&b1,
                     (void*)&Wih2, (void*)&Whh2, (void*)&b2,
                     (void*)&Wlin, (void*)&blin, (void*)&out, (void*)&hb };
    hipLaunchCooperativeKernel((const void*)lstm2_ef, dim3(NBLK), dim3(NTHR),
                               args, 0, stream);
}

// Round 15
// 8725.626 us; speedup vs baseline: 1.1983x; 1.1983x over previous
//
#include <hip/hip_runtime.h>

typedef _Float16 half8 __attribute__((ext_vector_type(8)));
typedef float    f32x4 __attribute__((ext_vector_type(4)));

static constexpr int S_ = 2048;   // sequence length
static constexpr int B_ = 64;     // batch
static constexpr int D_ = 128;    // input dim
static constexpr int H_ = 256;    // hidden
static constexpr int C_ = 10;     // classes

static constexpr int NBLK = 64;   // 32 L1-role + 32 L2-role (R8 structure)
static constexpr int NTHR = 512;  // 8 waves (R8/R11-exact wave structure)
static constexpr int HHALF = B_ * H_;   // halves per h slot (32 KB)

// R23 = R19 byte-exact (session best, 8815 us). R20/R21/R22 all regressed;
// the remaining ~4.3 us/step is a cross-XCD communication-latency floor
// (producer drain -> flag propagation -> consumer detect -> fresh-line
// fetch), not a PMC-visible resource limit (HBM 2.3%, MFMA 1%, VALU 7.5%).
//
// R19 structure: R18 + poll/publish wave split -- the flag POLL for
// iteration t+1 runs on WAVE 1 at the END of iteration t, concurrent with
// wave 0's publish+drain+flag; the join barrier merges them. Head on L2
// waves 2-6 with 1-RT batched loads. 16B publish via wave-0 stg16 + solo
// drain (store path must stay >=16B contiguous; 8B scatter = write
// amplification, R15/R17). Full x prefetch in registers (R16). s_sleep
// poll backoff (R16).
//
// Per-block epoch flags, one 64B line each (R7/R8-proven).
__device__ __attribute__((aligned(64))) unsigned g_f[NBLK * 16];

#define LD_AG(p)    __hip_atomic_load((p), __ATOMIC_RELAXED, __HIP_MEMORY_SCOPE_AGENT)
#define ST_AG(p, v) __hip_atomic_store((p), (v), __ATOMIC_RELAXED, __HIP_MEMORY_SCOPE_AGENT)

__device__ __forceinline__ float fs(float v) { return 1.0f / (1.0f + __expf(-v)); }
__device__ __forceinline__ float ft(float v) { return 1.0f - 2.0f / (__expf(2.0f * v) + 1.0f); }

// 8x 16B LLC-coherent loads in ONE asm block, completed by the trailing
// vmcnt(0): the compiler/RA can never read an un-landed destination register.
__device__ __forceinline__ void ldg16x8(half8* r,
    const _Float16* p0, const _Float16* p1, const _Float16* p2, const _Float16* p3,
    const _Float16* p4, const _Float16* p5, const _Float16* p6, const _Float16* p7)
{
    asm volatile(
        "global_load_dwordx4 %0, %8, off sc0 sc1\n\t"
        "global_load_dwordx4 %1, %9, off sc0 sc1\n\t"
        "global_load_dwordx4 %2, %10, off sc0 sc1\n\t"
        "global_load_dwordx4 %3, %11, off sc0 sc1\n\t"
        "global_load_dwordx4 %4, %12, off sc0 sc1\n\t"
        "global_load_dwordx4 %5, %13, off sc0 sc1\n\t"
        "global_load_dwordx4 %6, %14, off sc0 sc1\n\t"
        "global_load_dwordx4 %7, %15, off sc0 sc1\n\t"
        "s_waitcnt vmcnt(0)"
        : "=&v"(r[0]), "=&v"(r[1]), "=&v"(r[2]), "=&v"(r[3]),
          "=&v"(r[4]), "=&v"(r[5]), "=&v"(r[6]), "=&v"(r[7])
        : "v"(p0), "v"(p1), "v"(p2), "v"(p3),
          "v"(p4), "v"(p5), "v"(p6), "v"(p7)
        : "memory");
}

// 16x 16B LLC-coherent loads (8 fragments from pa, 8 from pb; fragment stride
// 4096 B) in ONE asm block with ONE trailing vmcnt(0) (R14-proven).
__device__ __forceinline__ void ldg16x8x2(half8* r,
                                          const _Float16* pa, const _Float16* pb)
{
    const _Float16* a0 = pa + 2048;  const _Float16* a1 = pa + 6144;
    const _Float16* a2 = pa + 10240; const _Float16* a3 = pa + 14336;
    const _Float16* b0 = pb + 2048;  const _Float16* b1 = pb + 6144;
    const _Float16* b2 = pb + 10240; const _Float16* b3 = pb + 14336;
    asm volatile(
        "global_load_dwordx4 %0, %16, off offset:-4096 sc0 sc1\n\t"
        "global_load_dwordx4 %1, %16, off sc0 sc1\n\t"
        "global_load_dwordx4 %2, %17, off offset:-4096 sc0 sc1\n\t"
        "global_load_dwordx4 %3, %17, off sc0 sc1\n\t"
        "global_load_dwordx4 %4, %18, off offset:-4096 sc0 sc1\n\t"
        "global_load_dwordx4 %5, %18, off sc0 sc1\n\t"
        "global_load_dwordx4 %6, %19, off offset:-4096 sc0 sc1\n\t"
        "global_load_dwordx4 %7, %19, off sc0 sc1\n\t"
        "global_load_dwordx4 %8, %20, off offset:-4096 sc0 sc1\n\t"
        "global_load_dwordx4 %9, %20, off sc0 sc1\n\t"
        "global_load_dwordx4 %10, %21, off offset:-4096 sc0 sc1\n\t"
        "global_load_dwordx4 %11, %21, off sc0 sc1\n\t"
        "global_load_dwordx4 %12, %22, off offset:-4096 sc0 sc1\n\t"
        "global_load_dwordx4 %13, %22, off sc0 sc1\n\t"
        "global_load_dwordx4 %14, %23, off offset:-4096 sc0 sc1\n\t"
        "global_load_dwordx4 %15, %23, off sc0 sc1\n\t"
        "s_waitcnt vmcnt(0)"
        : "=&v"(r[0]),  "=&v"(r[1]),  "=&v"(r[2]),  "=&v"(r[3]),
          "=&v"(r[4]),  "=&v"(r[5]),  "=&v"(r[6]),  "=&v"(r[7]),
          "=&v"(r[8]),  "=&v"(r[9]),  "=&v"(r[10]), "=&v"(r[11]),
          "=&v"(r[12]), "=&v"(r[13]), "=&v"(r[14]), "=&v"(r[15])
        : "v"(a0), "v"(a1), "v"(a2), "v"(a3),
          "v"(b0), "v"(b1), "v"(b2), "v"(b3)
        : "memory");
}

// 2x 16B LLC-coherent loads, one vmcnt (head path; R17/R18-verified).
__device__ __forceinline__ void ldg16x2(half8* r,
                                        const _Float16* p0, const _Float16* p1)
{
    asm volatile(
        "global_load_dwordx4 %0, %2, off sc0 sc1\n\t"
        "global_load_dwordx4 %1, %3, off sc0 sc1\n\t"
        "s_waitcnt vmcnt(0)"
        : "=&v"(r[0]), "=&v"(r[1])
        : "v"(p0), "v"(p1)
        : "memory");
}

// 16B LLC-coherent store (publish path; R12/R14/R16-verified). The caller's
// trailing s_waitcnt vmcnt(0) orders it before the flag store.
__device__ __forceinline__ void stg16(_Float16* p, half8 v) {
    asm volatile("global_store_dwordx4 %0, %1, off sc0 sc1"
                 :: "v"(p), "v"(v) : "memory");
}

__device__ __forceinline__ half8 cvt8(float4 a, float4 b) {
    half8 r;
    r[0] = (_Float16)a.x; r[1] = (_Float16)a.y; r[2] = (_Float16)a.z; r[3] = (_Float16)a.w;
    r[4] = (_Float16)b.x; r[5] = (_Float16)b.y; r[6] = (_Float16)b.z; r[7] = (_Float16)b.w;
    return r;
}

__global__ __launch_bounds__(NTHR, 1)
void lstm2_ef(const float* __restrict__ x,
              const float* __restrict__ Wih1, const float* __restrict__ Whh1,
              const float* __restrict__ b1,
              const float* __restrict__ Wih2, const float* __restrict__ Whh2,
              const float* __restrict__ b2,
              const float* __restrict__ Wlin, const float* __restrict__ blin,
              float* __restrict__ out, _Float16* __restrict__ hb)
{
    const int bid = blockIdx.x, tid = threadIdx.x;
    const bool isL2 = (bid >= 32);
    const int blk  = bid & 31;                   // 0..31 within role
    const int lane = tid & 63, w = tid >> 6;     // 8 waves
    const int mt   = w & 3;                      // M-tile: batches mt*16..+15
    const int nt   = w >> 2;                     // N-tile 0/1
    const int n    = lane & 15;                  // n-row within tile
    const int kg   = lane >> 4;                  // k-group 0..3
    const int c4   = n >> 2, gate = n & 3;       // n = col4*4 + gate
    const int lc   = nt * 4 + c4;                // local col 0..7
    const int col  = blk * 8 + lc;               // hidden column 0..255
    const int rowg = gate * H_ + col;            // global W gate-row
    const int batchA = mt * 16 + n;              // A-frag row = batch

    _Float16* h1raw = hb;                 // [3][HHALF] each
    _Float16* h1t   = hb + 3 * HHALF;
    _Float16* h2raw = hb + 6 * HHALF;
    _Float16* h2t   = hb + 9 * HHALF;

    __shared__ __align__(16) _Float16 sh[2][B_][8];   // [raw|tanh][batch][local col]

    const unsigned base = LD_AG(&g_f[bid * 16]);   // uniform at launch boundary

    // zero h state via agent-scope stores: 12 slots * 32 KB = 49152 doubles
    { double* z = (double*)hb;
      for (int i = bid * NTHR + tid; i < 49152; i += NBLK * NTHR) ST_AG(z + i, 0.0); }

    // ---- weight-stationary B-fragments in VGPRs (loaded once; R8-verbatim) ----
    half8 bfrag[16];
    if (!isL2) {
        #pragma unroll
        for (int kt = 0; kt < 4; ++kt) {     // Wih1 [4H][128]
            const float* p = Wih1 + (size_t)rowg * D_ + kt * 32 + kg * 8;
            bfrag[kt] = cvt8(*(const float4*)p, *(const float4*)(p + 4));
        }
        #pragma unroll
        for (int kt = 4; kt < 12; ++kt) {    // Whh1 [4H][256]
            const float* p = Whh1 + (size_t)rowg * H_ + (kt - 4) * 32 + kg * 8;
            bfrag[kt] = cvt8(*(const float4*)p, *(const float4*)(p + 4));
        }
    } else {
        #pragma unroll
        for (int kt = 0; kt < 8; ++kt) {     // Wih2 [4H][256]
            const float* p = Wih2 + (size_t)rowg * H_ + kt * 32 + kg * 8;
            bfrag[kt] = cvt8(*(const float4*)p, *(const float4*)(p + 4));
        }
        #pragma unroll
        for (int kt = 8; kt < 16; ++kt) {    // Whh2 [4H][256]
            const float* p = Whh2 + (size_t)rowg * H_ + (kt - 8) * 32 + kg * 8;
            bfrag[kt] = cvt8(*(const float4*)p, *(const float4*)(p + 4));
        }
    }
    const float bias_n = isL2 ? b2[rowg] : b1[rowg];

    // publish init (zero-state visible): all waves' zero stores must be acked
    __syncthreads();                 // full-block vmcnt(0) drain before barrier
    if (tid == 0) ST_AG(&g_f[bid * 16], base + 1u);

    float cr[4] = {0.f, 0.f, 0.f, 0.f};   // cell state

    // x prefetch registers (L1 blocks only): FULL x fragments for t (R16)
    float4 xf[8];
    if (!isL2) {
        const float* xr = x + (size_t)batchA * D_;   // t = 0
        #pragma unroll
        for (int q = 0; q < 4; ++q) {
            xf[2 * q]     = *(const float4*)(xr + q * 32 + kg * 8);
            xf[2 * q + 1] = *(const float4*)(xr + q * 32 + kg * 8 + 4);
        }
    }

    // ---- prologue poll for iteration 0 (original t==0 semantics: all
    // targets et1 = base+1, since zero-init was written by ALL blocks) ----
    {
        const unsigned et1 = base + 1u;
        if (tid >= 64 && tid < 128) {
            while ((int)(LD_AG(&g_f[(tid & 63) * 16]) - et1) < 0)
                __builtin_amdgcn_s_sleep(1);
        }
        __syncthreads();
    }

    int w3 = 0;   // t % 3

    // iteration t: L1 computes h1[t] (slot w3); L2 computes h2[t-1] (slot r1)
    // reading h1t[r1], h2raw[r2]; head (on L2) computes out[t-2] from h2t[r2].
    // Entry invariant: the poll for iteration t passed before the barrier
    // that precedes this iteration's compute.
    for (int t = 0; t <= S_ + 1; ++t) {
        const int r1 = (w3 == 0) ? 2 : w3 - 1;   // (t-1) % 3
        const int r2 = (w3 == 2) ? 0 : w3 + 1;   // (t-2) % 3

        if (!isL2) {
            if (t < S_) {
                half8 af[12];
                {   // x part: ALL from prefetch registers (no loads on chain)
                    af[0] = cvt8(xf[0], xf[1]);
                    af[1] = cvt8(xf[2], xf[3]);
                    af[2] = cvt8(xf[4], xf[5]);
                    af[3] = cvt8(xf[6], xf[7]);
                }
                // h part: K-tile (kt,kg) -> block region jb = kt*4+kg;
                // kt stride in halves = 4*64*8 = 2048
                const _Float16* hp = h1raw + r1 * HHALF + (((size_t)kg * 64 + batchA) << 3);
                ldg16x8(&af[4], hp,          hp + 2048,  hp + 4096,  hp + 6144,
                                hp + 8192,   hp + 10240, hp + 12288, hp + 14336);
                f32x4 accA = {0.f, 0.f, 0.f, 0.f}, accB = {0.f, 0.f, 0.f, 0.f};
                #pragma unroll
                for (int kt = 0; kt < 12; kt += 2) {
                    accA = __builtin_amdgcn_mfma_f32_16x16x32_f16(af[kt],     bfrag[kt],     accA, 0, 0, 0);
                    accB = __builtin_amdgcn_mfma_f32_16x16x32_f16(af[kt + 1], bfrag[kt + 1], accB, 0, 0, 0);
                }
                #pragma unroll
                for (int r = 0; r < 4; ++r) {
                    const float pre = accA[r] + accB[r] + bias_n;
                    const float av  = (gate == 2) ? ft(pre) : fs(pre);
                    const int lb = (lane & 48) | (c4 << 2);
                    const float gi = __shfl(av, lb | 0, 64), gf = __shfl(av, lb | 1, 64);
                    const float gg = __shfl(av, lb | 2, 64), go = __shfl(av, lb | 3, 64);
                    const float cn = gf * cr[r] + gi * gg; cr[r] = cn;
                    const float hv = go * ft(cn);
                    const int bD = mt * 16 + kg * 4 + r;
                    if (gate == 0) sh[0][bD][lc] = (_Float16)hv;
                    if (gate == 1) sh[1][bD][lc] = (_Float16)ft(hv);
                }
            }
        } else {
            if (t >= 1 && t <= S_) {
                half8 af[16];
                const _Float16* h1p = h1t   + r1 * HHALF + (((size_t)kg * 64 + batchA) << 3);
                const _Float16* h2p = h2raw + r2 * HHALF + (((size_t)kg * 64 + batchA) << 3);
                ldg16x8x2(af, h1p, h2p);   // all 16 fragments, ONE vmcnt(0)
                f32x4 accA = {0.f, 0.f, 0.f, 0.f}, accB = {0.f, 0.f, 0.f, 0.f};
                #pragma unroll
                for (int kt = 0; kt < 16; kt += 2) {
                    accA = __builtin_amdgcn_mfma_f32_16x16x32_f16(af[kt],     bfrag[kt],     accA, 0, 0, 0);
                    accB = __builtin_amdgcn_mfma_f32_16x16x32_f16(af[kt + 1], bfrag[kt + 1], accB, 0, 0, 0);
                }
                #pragma unroll
                for (int r = 0; r < 4; ++r) {
                    const float pre = accA[r] + accB[r] + bias_n;
                    const float av  = (gate == 2) ? ft(pre) : fs(pre);
                    const int lb = (lane & 48) | (c4 << 2);
                    const float gi = __shfl(av, lb | 0, 64), gf = __shfl(av, lb | 1, 64);
                    const float gg = __shfl(av, lb | 2, 64), go = __shfl(av, lb | 3, 64);
                    const float cn = gf * cr[r] + gi * gg; cr[r] = cn;
                    const float hv = go * ft(cn);
                    const int bD = mt * 16 + kg * 4 + r;
                    if (gate == 0) sh[0][bD][lc] = (_Float16)hv;
                    if (gate == 1) sh[1][bD][lc] = (_Float16)ft(hv);
                }
            }
        }

        __syncthreads();   // LDS tile complete (lgkm drain + barrier)

        // ---- wave 0: publish + drain + EARLY FLAG ----
        if (tid < 64) {
            const int b = tid;
            bool doit; int slot;
            if (!isL2) { doit = (t < S_);            slot = w3; }
            else       { doit = (t >= 1 && t <= S_); slot = r1; }
            if (doit) {
                const half8 s0 = *(const half8*)&sh[0][b][0];
                const half8 s1 = *(const half8*)&sh[1][b][0];
                _Float16* braw = isL2 ? h2raw : h1raw;
                _Float16* btnh = isL2 ? h2t   : h1t;
                stg16(braw + slot * HHALF + ((blk * 64 + b) << 3), s0);
                stg16(btnh + slot * HHALF + ((blk * 64 + b) << 3), s1);
            }
            asm volatile("s_waitcnt vmcnt(0)" ::: "memory");
            __builtin_amdgcn_sched_barrier(0);
            if (tid == 0) ST_AG(&g_f[bid * 16], base + (unsigned)t + 2u);
        }

        // ---- wave 1: poll for iteration t+1, CONCURRENT with wave 0's
        // publish+drain (different lines). Targets = original scheme at t+1
        // (t+1 >= 1, so no t==0 case). Skipped after the last iteration. ----
        if (t < S_ + 1 && tid >= 64 && tid < 128) {
            const int l = tid & 63;
            const unsigned et1 = base + (unsigned)(t + 1) + 1u;
            const unsigned tg = (l < 32 || isL2) ? et1 : et1 - 1u;
            while ((int)(LD_AG(&g_f[l * 16]) - tg) < 0)
                __builtin_amdgcn_s_sleep(1);   // backoff: cut hot-line polls
        }

        // ---- post-flag work: overlaps peers' detect+load window ----
        // x prefetch for t+1 (L1 role): FULL fragments (all waves; wave 1
        // does it after its poll)
        if (!isL2 && t + 1 < S_) {
            const float* xr = x + ((size_t)(t + 1) * B_ + batchA) * D_;
            #pragma unroll
            for (int q = 0; q < 4; ++q) {
                xf[2 * q]     = *(const float4*)(xr + q * 32 + kg * 8);
                xf[2 * q + 1] = *(const float4*)(xr + q * 32 + kg * 8 + 4);
            }
        }
        // head (on L2, waves 2-6): out[t-2] = sigmoid(tanh(h2[t-2])@Wlin^T+blin)
        // Off waves 0/1 (publish and poll). Race-free: head(t) precedes our
        // flag(t+1), which gates any peer overwrite of h2t slot r2.
        if (isL2 && t >= 2) {
            const int hg = (tid >> 4) - 8;   // waves 2-6: groups 0..19
            if (hg >= 0 && hg < 20) {
                const int dot = blk * 20 + hg, cls = dot >> 6, ob = dot & 63, l16 = tid & 15;
                const _Float16* hB = h2t + r2 * HHALF;
                half8 v[2];
                ldg16x2(v, hB + (((2 * l16)     * 64 + ob) << 3),
                           hB + (((2 * l16 + 1) * 64 + ob) << 3));
                const float* wr = Wlin + (size_t)cls * H_ + l16 * 16;
                float p = 0.f;
                #pragma unroll
                for (int j = 0; j < 8; ++j) p += (float)v[0][j] * wr[j] + (float)v[1][j] * wr[8 + j];
                p += __shfl_xor(p, 1, 64); p += __shfl_xor(p, 2, 64);
                p += __shfl_xor(p, 4, 64); p += __shfl_xor(p, 8, 64);
                if (l16 == 0)
                    out[((size_t)(t - 2) * B_ + ob) * C_ + cls] = fs(p + blin[cls]);
            }
        }

        // join: wave 1's poll passed AND wave 0's publish drained+flagged.
        // Orders LDS-tile reuse and slot overwrites for iteration t+1.
        __syncthreads();

        w3 = r2;   // (t+1) % 3
    }
}

extern "C" void kernel_launch(void* const* d_in, const int* in_sizes, int n_in,
                              void* d_out, int out_size, void* d_ws, size_t ws_size,
                              hipStream_t stream)
{
    const float* x    = (const float*)d_in[0];
    const float* Wih1 = (const float*)d_in[1];
    const float* Whh1 = (const float*)d_in[2];
    const float* b1   = (const float*)d_in[3];
    const float* Wih2 = (const float*)d_in[4];
    const float* Whh2 = (const float*)d_in[5];
    const float* b2   = (const float*)d_in[6];
    const float* Wlin = (const float*)d_in[7];
    const float* blin = (const float*)d_in[8];
    float* out = (float*)d_out;
    _Float16* hb = (_Float16*)d_ws;

    void* args[] = { (void*)&x, (void*)&Wih1, (void*)&Whh1, (void*)&b1,
                     (void*)&Wih2, (void*)&Whh2, (void*)&b2,
                     (void*)&Wlin, (void*)&blin, (void*)&out, (void*)&hb };
    hipLaunchCooperativeKernel((const void*)lstm2_ef, dim3(NBLK), dim3(NTHR),
                               args, 0, stream);
}